// Round 7
// baseline (893.149 us; speedup 1.0000x reference)
//
#include <hip/hip_runtime.h>
#include <hip/hip_bf16.h>
#include <hip/hip_fp16.h>
#include <math.h>

#define B_ 128
#define S_ 512
#define EMB_ 200
#define HID_ 128
#define NT_ 20
#define G4_ 512   // 4*HID
#define KP_ 224   // K padded to 7*32

typedef short bf16x8 __attribute__((ext_vector_type(8)));
typedef float f32x4 __attribute__((ext_vector_type(4)));

// single-instruction f16x2 dot with f32 accumulate: c += a.x*b.x + a.y*b.y
__device__ __forceinline__ float dot2_(unsigned a, unsigned b, float c) {
    asm("v_dot2_f32_f16 %0, %1, %2, %0" : "+v"(c) : "v"(a), "v"(b));
    return c;
}

__device__ __forceinline__ float bf2f(unsigned u) {
    union { unsigned u; float f; } cv;
    cv.u = u << 16;
    return cv.f;
}
__device__ __forceinline__ unsigned packh2(float a, float b) {
    return ((unsigned)__half_as_ushort(__float2half(b)) << 16)
         | (unsigned)__half_as_ushort(__float2half(a));
}
__device__ __forceinline__ unsigned short f2bf(float f) {
    __hip_bfloat16 h = __float2bfloat16(f);
    unsigned short u;
    __builtin_memcpy(&u, &h, 2);
    return u;
}

// ---------- detect mask dtype (bool bytes vs int32) ----------
__global__ void k_detect(const unsigned char* mask, int* flag) {
    __shared__ int partial[4];
    int tid = threadIdx.x;
    int s = 0;
    for (int i = tid; i < B_ * S_; i += 256) {
        if (i & 3) s += mask[i];
    }
    for (int m = 32; m >= 1; m >>= 1) s += __shfl_xor(s, m);
    if ((tid & 63) == 0) partial[tid >> 6] = s;
    __syncthreads();
    if (tid == 0) {
        int tot = partial[0] + partial[1] + partial[2] + partial[3];
        flag[0] = (tot > 0) ? 1 : 0;  // 1 => 1-byte bool layout, 0 => int32
    }
}

// ---------- K0: prep W_ih -> bf16 [512][224] (zero-padded), bias = b_ih+b_hh ----------
__global__ void k_prep(const float* __restrict__ W_ih, const float* __restrict__ b_ih,
                       const float* __restrict__ b_hh, __hip_bfloat16* __restrict__ Wb,
                       float* __restrict__ biasb) {
    int i = blockIdx.x * 256 + threadIdx.x;
    if (i < G4_ * KP_) {
        int g = i / KP_, k = i - g * KP_;
        float v = (k < EMB_) ? W_ih[g * EMB_ + k] : 0.f;
        Wb[i] = __float2bfloat16(v);
    }
    if (i < G4_) biasb[i] = b_ih[i] + b_hh[i];
}

// ---------- K1: xg = gather(embedding) @ W_ih^T + bias, via MFMA bf16 ----------
// Output stored PERMUTED for k_lstm's lane layout: pos(g) = (g&127)*4 + (g>>7).
__global__ __launch_bounds__(256, 2) void k_xg(const int* __restrict__ sentence,
                                               const float* __restrict__ embedding,
                                               const __hip_bfloat16* __restrict__ Wb,
                                               const float* __restrict__ biasb,
                                               __hip_bfloat16* __restrict__ xg) {
    __shared__ short Bl[G4_ * 40];  // 40 KB
    __shared__ short Al[32 * 40];   // 2.5 KB
    __shared__ int ids_s[32];
    int tid = threadIdx.x;
    int m0 = blockIdx.x * 32;
    int lane = tid & 63;
    int gbase = (tid >> 6) * 128;
    if (tid < 32) ids_s[tid] = sentence[m0 + tid];
    __syncthreads();

    f32x4 acc0[8], acc1[8];
#pragma unroll
    for (int n = 0; n < 8; n++) {
        acc0[n] = (f32x4){0.f, 0.f, 0.f, 0.f};
        acc1[n] = (f32x4){0.f, 0.f, 0.f, 0.f};
    }
    int lrow = lane & 15, lk = lane >> 4;

    for (int c = 0; c < 7; c++) {
        int k0 = c * 32;
#pragma unroll
        for (int i = 0; i < 8; i++) {
            int idx = tid + 256 * i;
            int row = idx >> 2, q = idx & 3;
            uint4 v = *(const uint4*)((const short*)Wb + (size_t)row * KP_ + k0 + q * 8);
            *(uint4*)(Bl + row * 40 + q * 8) = v;
        }
#pragma unroll
        for (int i = 0; i < 2; i++) {
            int j = tid + 256 * i;
            int row = j >> 4, kp = j & 15;
            int k = k0 + kp * 2;
            const float* e = embedding + (size_t)ids_s[row] * EMB_;
            float v0 = (k < EMB_) ? e[k] : 0.f;
            float v1 = (k + 1 < EMB_) ? e[k + 1] : 0.f;
            unsigned u = (unsigned)f2bf(v0) | ((unsigned)f2bf(v1) << 16);
            *(unsigned*)(Al + row * 40 + kp * 2) = u;
        }
        __syncthreads();
        bf16x8 a0 = *(const bf16x8*)(Al + lrow * 40 + lk * 8);
        bf16x8 a1 = *(const bf16x8*)(Al + (lrow + 16) * 40 + lk * 8);
#pragma unroll
        for (int n = 0; n < 8; n++) {
            bf16x8 bfr = *(const bf16x8*)(Bl + (gbase + n * 16 + lrow) * 40 + lk * 8);
            acc0[n] = __builtin_amdgcn_mfma_f32_16x16x32_bf16(a0, bfr, acc0[n], 0, 0, 0);
            acc1[n] = __builtin_amdgcn_mfma_f32_16x16x32_bf16(a1, bfr, acc1[n], 0, 0, 0);
        }
        __syncthreads();
    }
    int rbase = m0 + lk * 4;
#pragma unroll
    for (int n = 0; n < 8; n++) {
        int g = gbase + n * 16 + lrow;
        float bv = biasb[g];
        int pos = ((g & 127) << 2) | (g >> 7);  // k_lstm lane permutation
#pragma unroll
        for (int r = 0; r < 4; r++) {
            xg[(size_t)(rbase + r) * G4_ + pos] = __float2bfloat16(acc0[n][r] + bv);
            xg[(size_t)(rbase + r + 16) * G4_ + pos] = __float2bfloat16(acc1[n][r] + bv);
        }
    }
}

// ---------- K2: per-batch LSTM scan — 1 barrier/step, inline-asm v_dot2 ----------
// lane = el*8 + gt*2 + half. 32 pinned f16x2 weight regs (proven resident at this
// count). Dot: 32 v_dot2_f32_f16 (single-instr, 4 independent acc chains).
// Activation branchless, no clamps (f32 exp saturates safely). h stored as ushort:
// gt0/half0 lane -> LDS (double-buffered), gt0/half1 lane -> global. One barrier.
__global__ __launch_bounds__(1024) __attribute__((amdgpu_waves_per_eu(4, 4)))
void k_lstm(const __hip_bfloat16* __restrict__ xg,
            const float* __restrict__ W_hh,
            unsigned* __restrict__ h2_out) {
    __shared__ ushort hbuf[2][HID_];  // h as f16, double-buffered
    int b = blockIdx.x, tid = threadIdx.x;
    int wv = tid >> 6, lane = tid & 63;
    int el = lane >> 3, gt = (lane >> 1) & 3, half = lane & 1;
    int e = (wv << 3) | el;             // hidden element 0..127
    int g = (gt << 7) | e;              // gate row in W_hh

    unsigned w2[32];
    const float2* wrow = (const float2*)(W_hh + (size_t)g * HID_ + half * 64);
#pragma unroll
    for (int k = 0; k < 32; k++) {
        float2 f = wrow[k];
        w2[k] = packh2(f.x, f.y);
    }
#pragma unroll
    for (int k = 0; k < 32; k++) asm("" : "+v"(w2[k]));

    if (tid < HID_) hbuf[0][tid] = 0;
    float c = 0.f;
    const ushort* xp = (const ushort*)(xg) + (size_t)b * S_ * G4_ + (tid >> 1);
    ushort* hgp = (ushort*)h2_out + (size_t)b * S_ * HID_ + e;
    bool isg = (gt == 2);
    int wLDS = ((lane & 7) == 0);       // gt0, half0
    int wGLB = ((lane & 7) == 1);       // gt0, half1
    __syncthreads();

    unsigned xr = *xp;
    for (int t = 0; t < S_; t++) {
        xp += G4_;
        unsigned xr_next = *xp;  // last iter overreads 1 row into ws (unused) — safe

        const uint4* hp = (const uint4*)(hbuf[t & 1]) + (half << 3);
        float a0 = 0.f, a1 = 0.f, a2 = 0.f, a3 = 0.f;
#pragma unroll
        for (int q = 0; q < 8; q++) {
            uint4 hh = hp[q];  // 2 broadcast addrs/wave: free
            a0 = dot2_(w2[4 * q + 0], hh.x, a0);
            a1 = dot2_(w2[4 * q + 1], hh.y, a1);
            a2 = dot2_(w2[4 * q + 2], hh.z, a2);
            a3 = dot2_(w2[4 * q + 3], hh.w, a3);
        }
        float acc = (a0 + a1) + (a2 + a3);
        acc += __shfl_xor(acc, 1);      // combine K-halves (lane^1)
        float pre = bf2f(xr) + acc;
        // branchless sigmoid/tanh, clamp-free (exp saturates safely in f32)
        float xs = isg ? 2.f * pre : pre;
        float r = 1.f / (1.f + __expf(-xs));
        float act = isg ? 2.f * r - 1.f : r;

        float aF = __shfl_xor(act, 2);  // gt^1
        float aG = __shfl_xor(act, 4);  // gt^2
        float aO = __shfl_xor(aF, 4);   // gt^3
        // valid on gt==0 lanes (both halves): i=act, f=aF, g=aG, o=aO
        c = aF * c + act * aG;
        float th = 2.f / (1.f + __expf(-2.f * c)) - 1.f;
        float h = aO * th;
        ushort hu = __half_as_ushort(__float2half(h));
        if (wLDS) hbuf[(t + 1) & 1][e] = hu;
        if (wGLB) *hgp = hu;            // fire-and-forget
        hgp += HID_;
        __syncthreads();
        xr = xr_next;
    }
}

// ---------- K2b: emissions em[row][tag] = dot(h[row], W_dec[tag]) + b_dec ----------
__global__ __launch_bounds__(320) void k_em(const unsigned* __restrict__ h2,
                                            const float* __restrict__ W_dec,
                                            const float* __restrict__ b_dec,
                                            float* __restrict__ em) {
    int half = threadIdx.x / 160;
    int r = threadIdx.x % 160;
    int tag = r >> 3, l8 = r & 7;
    const float* wd = W_dec + tag * HID_ + l8 * 16;
    float ws[16];
#pragma unroll
    for (int q = 0; q < 16; q++) ws[q] = wd[q];
    float bd = b_dec[tag];
    int row0 = blockIdx.x * 16 + half * 8;
    for (int rp = 0; rp < 8; rp++) {
        int row = row0 + rp;
        const uint4* h4 = (const uint4*)(h2 + (size_t)row * 64 + l8 * 8);
        uint4 a = h4[0], bq = h4[1];
        unsigned hv[8] = {a.x, a.y, a.z, a.w, bq.x, bq.y, bq.z, bq.w};
        float pacc = 0.f;
#pragma unroll
        for (int q = 0; q < 8; q++) {
            float lo = __half2float(__ushort_as_half((unsigned short)(hv[q] & 0xffffu)));
            float hi = __half2float(__ushort_as_half((unsigned short)(hv[q] >> 16)));
            pacc += lo * ws[2 * q] + hi * ws[2 * q + 1];
        }
        pacc += __shfl_xor(pacc, 1);
        pacc += __shfl_xor(pacc, 2);
        pacc += __shfl_xor(pacc, 4);
        if (l8 == 0) em[(size_t)row * NT_ + tag] = pacc + bd;
    }
}

// ---------- K3: per-batch CRF numerator + forward algorithm ----------
__global__ __launch_bounds__(256, 2) void k_crf(const float* __restrict__ em,
                                                const int* __restrict__ tags,
                                                const void* __restrict__ mask,
                                                const int* __restrict__ flag,
                                                const float* __restrict__ start_trans,
                                                const float* __restrict__ end_trans,
                                                const float* __restrict__ trans,
                                                float* __restrict__ nll) {
    __shared__ float em_s[S_ * NT_];     // 40 KB
    __shared__ float trans_s[NT_ * NT_];
    __shared__ float score[2][NT_];
    __shared__ int tags_s[S_];
    __shared__ unsigned char mask_s[S_];
    __shared__ float fin[NT_];
    __shared__ float num_sh;

    int b = blockIdx.x;
    int tid = threadIdx.x;
    const float* emb_ = em + (size_t)b * S_ * NT_;

    for (int i = tid; i < S_ * NT_; i += 256) em_s[i] = emb_[i];
    for (int i = tid; i < NT_ * NT_; i += 256) trans_s[i] = trans[i];
    for (int i = tid; i < S_; i += 256) tags_s[i] = tags[b * S_ + i];
    int fl = flag[0];
    for (int i = tid; i < S_; i += 256) {
        mask_s[i] = fl ? ((const unsigned char*)mask)[b * S_ + i]
                       : (unsigned char)(((const int*)mask)[b * S_ + i] != 0);
    }
    __syncthreads();
    if (tid < NT_) score[0][tid] = start_trans[tid] + em_s[tid];
    float num = 0.f;
    int lastTag = 0;
    if (tid == 192) {
        lastTag = tags_s[0];
        num = start_trans[lastTag] + em_s[lastTag];
    }
    __syncthreads();

    int tag = tid >> 3, l8 = tid & 7;
    int cur = 0;
    for (int t = 1; t < S_; t++) {
        if (tid < NT_ * 8) {
            float v0 = score[cur][l8] + trans_s[l8 * NT_ + tag];
            float v1 = score[cur][l8 + 8] + trans_s[(l8 + 8) * NT_ + tag];
            float v2 = (l8 < 4) ? score[cur][l8 + 16] + trans_s[(l8 + 16) * NT_ + tag]
                                : -INFINITY;
            float m = fmaxf(fmaxf(v0, v1), v2);
            m = fmaxf(m, __shfl_xor(m, 4));
            m = fmaxf(m, __shfl_xor(m, 2));
            m = fmaxf(m, __shfl_xor(m, 1));
            float s = __expf(v0 - m) + __expf(v1 - m) + ((l8 < 4) ? __expf(v2 - m) : 0.f);
            s += __shfl_xor(s, 4);
            s += __shfl_xor(s, 2);
            s += __shfl_xor(s, 1);
            if (l8 == 0) {
                float nxt = m + __logf(s) + em_s[t * NT_ + tag];
                score[cur ^ 1][tag] = mask_s[t] ? nxt : score[cur][tag];
            }
        }
        if (tid == 192) {
            if (mask_s[t]) {
                int tg = tags_s[t];
                num += trans_s[lastTag * NT_ + tg] + em_s[t * NT_ + tg];
                lastTag = tg;
            }
        }
        __syncthreads();
        cur ^= 1;
    }
    if (tid == 192) num_sh = num + end_trans[lastTag];
    if (tid < NT_) fin[tid] = score[cur][tid] + end_trans[tid];
    __syncthreads();
    if (tid == 0) {
        float m = fin[0];
#pragma unroll
        for (int i = 1; i < NT_; i++) m = fmaxf(m, fin[i]);
        float s = 0.f;
#pragma unroll
        for (int i = 0; i < NT_; i++) s += __expf(fin[i] - m);
        float den = m + __logf(s);
        nll[b] = den - num_sh;
    }
}

// ---------- K4: mean over batch ----------
__global__ void k_final(const float* __restrict__ nll, float* __restrict__ out) {
    __shared__ float sums[2];
    int tid = threadIdx.x;  // 128 threads
    float v = nll[tid];
    for (int m = 32; m >= 1; m >>= 1) v += __shfl_xor(v, m);
    if ((tid & 63) == 0) sums[tid >> 6] = v;
    __syncthreads();
    if (tid == 0) out[0] = (sums[0] + sums[1]) * (1.f / (float)B_);
}

extern "C" void kernel_launch(void* const* d_in, const int* in_sizes, int n_in,
                              void* d_out, int out_size, void* d_ws, size_t ws_size,
                              hipStream_t stream) {
    const int* sentence = (const int*)d_in[0];
    const int* tags = (const int*)d_in[1];
    const void* mask = d_in[2];
    const float* embedding = (const float*)d_in[3];
    const float* W_ih = (const float*)d_in[4];
    const float* W_hh = (const float*)d_in[5];
    const float* b_ih = (const float*)d_in[6];
    const float* b_hh = (const float*)d_in[7];
    const float* W_dec = (const float*)d_in[8];
    const float* b_dec = (const float*)d_in[9];
    const float* start_trans = (const float*)d_in[10];
    const float* end_trans = (const float*)d_in[11];
    const float* trans = (const float*)d_in[12];

    char* ws = (char*)d_ws;
    int* flag = (int*)ws;                                   // 4 B (pad to 256)
    __hip_bfloat16* xg = (__hip_bfloat16*)(ws + 256);       // B*S*512 bf16 = 64 MiB
    size_t off = 256 + (size_t)B_ * S_ * G4_ * 2;
    float* em = (float*)(ws + off);                         // B*S*20 f32 = 5 MiB
    off += (size_t)B_ * S_ * NT_ * 4;
    float* nllp = (float*)(ws + off);                       // 128 f32 (pad 512)
    off += 512;
    unsigned* h2_out = (unsigned*)(ws + off);               // B*S*64 u32 = 16 MiB
    off += (size_t)B_ * S_ * 64 * 4;
    __hip_bfloat16* Wb = (__hip_bfloat16*)(ws + off);       // 512*224 bf16 = 224 KB
    off += (size_t)G4_ * KP_ * 2;
    float* biasb = (float*)(ws + off);                      // 512 f32

    k_detect<<<1, 256, 0, stream>>>((const unsigned char*)mask, flag);
    k_prep<<<(G4_ * KP_ + 255) / 256, 256, 0, stream>>>(W_ih, b_ih, b_hh, Wb, biasb);
    k_xg<<<(B_ * S_) / 32, 256, 0, stream>>>(sentence, embedding, Wb, biasb, xg);
    k_lstm<<<B_, 1024, 0, stream>>>(xg, W_hh, h2_out);
    k_em<<<(B_ * S_) / 16, 320, 0, stream>>>(h2_out, W_dec, b_dec, em);
    k_crf<<<B_, 256, 0, stream>>>(em, tags, mask, flag, start_trans, end_trans, trans, nllp);
    k_final<<<1, 128, 0, stream>>>(nllp, (float*)d_out);
}

// Round 8
// 709.865 us; speedup vs baseline: 1.2582x; 1.2582x over previous
//
#include <hip/hip_runtime.h>
#include <hip/hip_bf16.h>
#include <hip/hip_fp16.h>
#include <math.h>

#define B_ 128
#define S_ 512
#define EMB_ 200
#define HID_ 128
#define NT_ 20
#define G4_ 512   // 4*HID
#define KP_ 224   // K padded to 7*32

typedef _Float16 f16x2_t __attribute__((ext_vector_type(2)));
typedef short bf16x8 __attribute__((ext_vector_type(8)));
typedef float f32x4 __attribute__((ext_vector_type(4)));

#if __has_builtin(__builtin_amdgcn_fdot2)
#define FDOT2(a, b, c) __builtin_amdgcn_fdot2(__builtin_bit_cast(f16x2_t, (a)), \
                                              __builtin_bit_cast(f16x2_t, (b)), (c), false)
#else
static __device__ __forceinline__ float fdot2_fb(unsigned a, unsigned b, float c) {
    float alo = __half2float(__ushort_as_half((unsigned short)(a & 0xffffu)));
    float ahi = __half2float(__ushort_as_half((unsigned short)(a >> 16)));
    float blo = __half2float(__ushort_as_half((unsigned short)(b & 0xffffu)));
    float bhi = __half2float(__ushort_as_half((unsigned short)(b >> 16)));
    return c + alo * blo + ahi * bhi;
}
#define FDOT2(a, b, c) fdot2_fb((a), (b), (c))
#endif

__device__ __forceinline__ float bf2f(unsigned u) {
    union { unsigned u; float f; } cv;
    cv.u = u << 16;
    return cv.f;
}
__device__ __forceinline__ unsigned packh2(float a, float b) {
    return ((unsigned)__half_as_ushort(__float2half(b)) << 16)
         | (unsigned)__half_as_ushort(__float2half(a));
}
__device__ __forceinline__ unsigned short f2bf(float f) {
    __hip_bfloat16 h = __float2bfloat16(f);
    unsigned short u;
    __builtin_memcpy(&u, &h, 2);
    return u;
}

// ---------- detect mask dtype (bool bytes vs int32) ----------
__global__ void k_detect(const unsigned char* mask, int* flag) {
    __shared__ int partial[4];
    int tid = threadIdx.x;
    int s = 0;
    for (int i = tid; i < B_ * S_; i += 256) {
        if (i & 3) s += mask[i];
    }
    for (int m = 32; m >= 1; m >>= 1) s += __shfl_xor(s, m);
    if ((tid & 63) == 0) partial[tid >> 6] = s;
    __syncthreads();
    if (tid == 0) {
        int tot = partial[0] + partial[1] + partial[2] + partial[3];
        flag[0] = (tot > 0) ? 1 : 0;  // 1 => 1-byte bool layout, 0 => int32
    }
}

// ---------- K0: prep W_ih -> bf16 [512][224] (zero-padded), bias = b_ih+b_hh ----------
__global__ void k_prep(const float* __restrict__ W_ih, const float* __restrict__ b_ih,
                       const float* __restrict__ b_hh, __hip_bfloat16* __restrict__ Wb,
                       float* __restrict__ biasb) {
    int i = blockIdx.x * 256 + threadIdx.x;
    if (i < G4_ * KP_) {
        int g = i / KP_, k = i - g * KP_;
        float v = (k < EMB_) ? W_ih[g * EMB_ + k] : 0.f;
        Wb[i] = __float2bfloat16(v);
    }
    if (i < G4_) biasb[i] = b_ih[i] + b_hh[i];
}

// ---------- K1: xg = gather(embedding) @ W_ih^T + bias, via MFMA bf16 (r5 exact) ----------
__global__ __launch_bounds__(256, 2) void k_xg(const int* __restrict__ sentence,
                                               const float* __restrict__ embedding,
                                               const __hip_bfloat16* __restrict__ Wb,
                                               const float* __restrict__ biasb,
                                               __hip_bfloat16* __restrict__ xg) {
    __shared__ short Bl[G4_ * 40];  // 40 KB
    __shared__ short Al[32 * 40];   // 2.5 KB
    __shared__ int ids_s[32];
    int tid = threadIdx.x;
    int m0 = blockIdx.x * 32;
    int lane = tid & 63;
    int gbase = (tid >> 6) * 128;
    if (tid < 32) ids_s[tid] = sentence[m0 + tid];
    __syncthreads();

    f32x4 acc0[8], acc1[8];
#pragma unroll
    for (int n = 0; n < 8; n++) {
        acc0[n] = (f32x4){0.f, 0.f, 0.f, 0.f};
        acc1[n] = (f32x4){0.f, 0.f, 0.f, 0.f};
    }
    int lrow = lane & 15, lk = lane >> 4;

    for (int c = 0; c < 7; c++) {
        int k0 = c * 32;
#pragma unroll
        for (int i = 0; i < 8; i++) {
            int idx = tid + 256 * i;
            int row = idx >> 2, q = idx & 3;
            uint4 v = *(const uint4*)((const short*)Wb + (size_t)row * KP_ + k0 + q * 8);
            *(uint4*)(Bl + row * 40 + q * 8) = v;
        }
#pragma unroll
        for (int i = 0; i < 2; i++) {
            int j = tid + 256 * i;
            int row = j >> 4, kp = j & 15;
            int k = k0 + kp * 2;
            const float* e = embedding + (size_t)ids_s[row] * EMB_;
            float v0 = (k < EMB_) ? e[k] : 0.f;
            float v1 = (k + 1 < EMB_) ? e[k + 1] : 0.f;
            unsigned u = (unsigned)f2bf(v0) | ((unsigned)f2bf(v1) << 16);
            *(unsigned*)(Al + row * 40 + kp * 2) = u;
        }
        __syncthreads();
        bf16x8 a0 = *(const bf16x8*)(Al + lrow * 40 + lk * 8);
        bf16x8 a1 = *(const bf16x8*)(Al + (lrow + 16) * 40 + lk * 8);
#pragma unroll
        for (int n = 0; n < 8; n++) {
            bf16x8 bfr = *(const bf16x8*)(Bl + (gbase + n * 16 + lrow) * 40 + lk * 8);
            acc0[n] = __builtin_amdgcn_mfma_f32_16x16x32_bf16(a0, bfr, acc0[n], 0, 0, 0);
            acc1[n] = __builtin_amdgcn_mfma_f32_16x16x32_bf16(a1, bfr, acc1[n], 0, 0, 0);
        }
        __syncthreads();
    }
    int rbase = m0 + lk * 4;
#pragma unroll
    for (int n = 0; n < 8; n++) {
        int g = gbase + n * 16 + lrow;
        float bv = biasb[g];
#pragma unroll
        for (int r = 0; r < 4; r++) {
            xg[(size_t)(rbase + r) * G4_ + g] = __float2bfloat16(acc0[n][r] + bv);
            xg[(size_t)(rbase + r + 16) * G4_ + g] = __float2bfloat16(acc1[n][r] + bv);
        }
    }
}

// ---------- K2: per-batch LSTM scan (r5 exact — fastest measured: 408 us) ----------
__global__ __launch_bounds__(1024) __attribute__((amdgpu_waves_per_eu(4, 4)))
void k_lstm(const __hip_bfloat16* __restrict__ xg,
            const float* __restrict__ W_hh,
            unsigned* __restrict__ h2_out) {
    __shared__ unsigned h2_lds[64];     // h packed f16x2: [j] = (h[2j], h[2j+1])
    __shared__ float part_lds[G4_];     // p=1 partial dot
    __shared__ float gate_lds[G4_];     // activated gates
    int b = blockIdx.x, tid = threadIdx.x;
    int wv = tid >> 6, lane = tid & 63;
    int p = wv >> 3;                    // K-half (wave-uniform)
    int g = ((wv & 7) << 6) | lane;     // gate 0..511

    unsigned w2[32];
    const float2* wrow = (const float2*)(W_hh + (size_t)g * HID_ + p * 64);
#pragma unroll
    for (int k = 0; k < 32; k++) {
        float2 f = wrow[k];
        w2[k] = packh2(f.x, f.y);
    }
#pragma unroll
    for (int k = 0; k < 32; k++) asm("" : "+v"(w2[k]));

    if (tid < 64) h2_lds[tid] = 0u;
    float c0 = 0.f, c1 = 0.f;
    const ushort* xgb = (const ushort*)(xg) + (size_t)b * S_ * G4_;
    unsigned* h2b = h2_out + (size_t)b * S_ * 64;
    __syncthreads();

    unsigned xr = (p == 0) ? (unsigned)xgb[g] : 0u;
    for (int t = 0; t < S_; t++) {
        unsigned xr_next = 0u;
        if (p == 0) {
            int tn = (t + 1 < S_) ? t + 1 : t;
            xr_next = xgb[(size_t)tn * G4_ + g];
        }
        float acc = 0.f;
        const uint4* hb4 = (const uint4*)(h2_lds + (p << 5));
#pragma unroll
        for (int q = 0; q < 8; q++) {
            uint4 hh = hb4[q];  // wave-uniform address: broadcast read
            acc = FDOT2(w2[4 * q + 0], hh.x, acc);
            acc = FDOT2(w2[4 * q + 1], hh.y, acc);
            acc = FDOT2(w2[4 * q + 2], hh.z, acc);
            acc = FDOT2(w2[4 * q + 3], hh.w, acc);
        }
        if (p == 1) part_lds[g] = acc;
        __syncthreads();
        if (p == 0) {
            float pre = bf2f(xr) + acc + part_lds[g];
            int gt = g >> 7;
            float xs = (gt == 2) ? 2.f * pre : pre;
            xs = fminf(fmaxf(xs, -30.f), 30.f);
            float r = 1.f / (1.f + __expf(-xs));
            gate_lds[g] = (gt == 2) ? 2.f * r - 1.f : r;
        }
        __syncthreads();
        if (tid < 64) {
            int j = tid;
            float2 iv = *(const float2*)(gate_lds + 2 * j);
            float2 fv = *(const float2*)(gate_lds + 128 + 2 * j);
            float2 gv = *(const float2*)(gate_lds + 256 + 2 * j);
            float2 ov = *(const float2*)(gate_lds + 384 + 2 * j);
            c0 = fv.x * c0 + iv.x * gv.x;
            c1 = fv.y * c1 + iv.y * gv.y;
            float h0 = ov.x * (2.f / (1.f + __expf(-2.f * c0)) - 1.f);
            float h1 = ov.y * (2.f / (1.f + __expf(-2.f * c1)) - 1.f);
            unsigned pk = packh2(h0, h1);
            h2_lds[j] = pk;
            h2b[(size_t)t * 64 + j] = pk;
        }
        __syncthreads();
        xr = xr_next;
    }
}

// ---------- K2b: emissions em[row][tag] = dot(h[row], W_dec[tag]) + b_dec (r5 exact) ----------
__global__ __launch_bounds__(320) void k_em(const unsigned* __restrict__ h2,
                                            const float* __restrict__ W_dec,
                                            const float* __restrict__ b_dec,
                                            float* __restrict__ em) {
    int half = threadIdx.x / 160;
    int r = threadIdx.x % 160;
    int tag = r >> 3, l8 = r & 7;
    const float* wd = W_dec + tag * HID_ + l8 * 16;
    float ws[16];
#pragma unroll
    for (int q = 0; q < 16; q++) ws[q] = wd[q];
    float bd = b_dec[tag];
    int row0 = blockIdx.x * 16 + half * 8;
    for (int rp = 0; rp < 8; rp++) {
        int row = row0 + rp;
        const uint4* h4 = (const uint4*)(h2 + (size_t)row * 64 + l8 * 8);
        uint4 a = h4[0], bq = h4[1];
        unsigned hv[8] = {a.x, a.y, a.z, a.w, bq.x, bq.y, bq.z, bq.w};
        float pacc = 0.f;
#pragma unroll
        for (int q = 0; q < 8; q++) {
            float lo = __half2float(__ushort_as_half((unsigned short)(hv[q] & 0xffffu)));
            float hi = __half2float(__ushort_as_half((unsigned short)(hv[q] >> 16)));
            pacc += lo * ws[2 * q] + hi * ws[2 * q + 1];
        }
        pacc += __shfl_xor(pacc, 1);
        pacc += __shfl_xor(pacc, 2);
        pacc += __shfl_xor(pacc, 4);
        if (l8 == 0) em[(size_t)row * NT_ + tag] = pacc + bd;
    }
}

// ---------- K3: CRF — ONE WAVE per batch. Numerator = parallel reduction (no
// recurrence: reference uses tags[t-1] directly). Forward loop: lane=tag holds
// trans column in 20 regs; per step 5 broadcast ds_read_b128 + in-lane LSE
// (explicit max/sum trees) + 1 ds_write. No cross-lane ops in the loop. ----------
__global__ __launch_bounds__(64) void k_crf(const float* __restrict__ em,
                                            const int* __restrict__ tags,
                                            const void* __restrict__ mask,
                                            const int* __restrict__ flag,
                                            const float* __restrict__ start_trans,
                                            const float* __restrict__ end_trans,
                                            const float* __restrict__ trans,
                                            float* __restrict__ nll) {
    __shared__ float em_s[S_ * NT_];     // 40 KB
    __shared__ float trans_s[NT_ * NT_];
    __shared__ int tags_s[S_];
    __shared__ unsigned char mask_s[S_];
    __shared__ __align__(16) float score_s[32];
    __shared__ float num_sh;

    int b = blockIdx.x;
    int lane = threadIdx.x;  // 64 threads = 1 wave
    const float4* e4 = (const float4*)(em + (size_t)b * S_ * NT_);
    float4* s4 = (float4*)em_s;
    for (int i = lane; i < S_ * NT_ / 4; i += 64) s4[i] = e4[i];
    for (int i = lane; i < NT_ * NT_; i += 64) trans_s[i] = trans[i];
    for (int i = lane; i < S_; i += 64) tags_s[i] = tags[b * S_ + i];
    int fl = flag[0];
    for (int i = lane; i < S_; i += 64) {
        mask_s[i] = fl ? ((const unsigned char*)mask)[b * S_ + i]
                       : (unsigned char)(((const int*)mask)[b * S_ + i] != 0);
    }
    __syncthreads();

    // ---- numerator: fully parallel over t ----
    float nsum = 0.f;
    int cnt = 0;
    for (int t = lane; t < S_; t += 64) cnt += mask_s[t];
    for (int t = 1 + lane; t < S_; t += 64) {
        if (mask_s[t]) {
            int tg = tags_s[t], pt = tags_s[t - 1];
            nsum += trans_s[pt * NT_ + tg] + em_s[t * NT_ + tg];
        }
    }
    for (int m = 32; m >= 1; m >>= 1) {
        nsum += __shfl_xor(nsum, m);
        cnt += __shfl_xor(cnt, m);
    }
    if (lane == 0) {
        int t0 = tags_s[0];
        num_sh = nsum + start_trans[t0] + em_s[t0] + end_trans[tags_s[cnt - 1]];
    }

    // ---- forward algorithm: serial over t, in-lane LSE ----
    int tag = (lane < NT_) ? lane : NT_ - 1;
    float tcol[NT_];
#pragma unroll
    for (int p = 0; p < NT_; p++) tcol[p] = trans_s[p * NT_ + tag];
    float sc = start_trans[tag] + em_s[tag];
    if (lane < NT_) score_s[lane] = sc;
    __syncthreads();

    for (int t = 1; t < S_; t++) {
        const float4* q4 = (const float4*)score_s;
        float4 q0 = q4[0], q1 = q4[1], q2 = q4[2], q3 = q4[3], q5 = q4[4];
        float v[NT_] = {q0.x + tcol[0],  q0.y + tcol[1],  q0.z + tcol[2],  q0.w + tcol[3],
                        q1.x + tcol[4],  q1.y + tcol[5],  q1.z + tcol[6],  q1.w + tcol[7],
                        q2.x + tcol[8],  q2.y + tcol[9],  q2.z + tcol[10], q2.w + tcol[11],
                        q3.x + tcol[12], q3.y + tcol[13], q3.z + tcol[14], q3.w + tcol[15],
                        q5.x + tcol[16], q5.y + tcol[17], q5.z + tcol[18], q5.w + tcol[19]};
        float mx[NT_];
#pragma unroll
        for (int p = 0; p < NT_; p++) mx[p] = v[p];
#pragma unroll
        for (int n = NT_; n > 1; n = (n + 1) >> 1) {
#pragma unroll
            for (int i = 0; i < (n >> 1); i++) mx[i] = fmaxf(mx[i], mx[n - 1 - i]);
        }
        float ex[NT_];
#pragma unroll
        for (int p = 0; p < NT_; p++) ex[p] = __expf(v[p] - mx[0]);
#pragma unroll
        for (int n = NT_; n > 1; n = (n + 1) >> 1) {
#pragma unroll
            for (int i = 0; i < (n >> 1); i++) ex[i] += ex[n - 1 - i];
        }
        float nxt = mx[0] + __logf(ex[0]) + em_s[t * NT_ + tag];
        sc = mask_s[t] ? nxt : sc;
        __syncthreads();               // 1-wave block: near-free, orders LDS
        if (lane < NT_) score_s[lane] = sc;
        __syncthreads();
    }

    if (lane < NT_) score_s[lane] = sc + end_trans[tag];
    __syncthreads();
    if (lane == 0) {
        float m = score_s[0];
#pragma unroll
        for (int i = 1; i < NT_; i++) m = fmaxf(m, score_s[i]);
        float s = 0.f;
#pragma unroll
        for (int i = 0; i < NT_; i++) s += __expf(score_s[i] - m);
        nll[b] = (m + __logf(s)) - num_sh;
    }
}

// ---------- K4: mean over batch ----------
__global__ void k_final(const float* __restrict__ nll, float* __restrict__ out) {
    __shared__ float sums[2];
    int tid = threadIdx.x;  // 128 threads
    float v = nll[tid];
    for (int m = 32; m >= 1; m >>= 1) v += __shfl_xor(v, m);
    if ((tid & 63) == 0) sums[tid >> 6] = v;
    __syncthreads();
    if (tid == 0) out[0] = (sums[0] + sums[1]) * (1.f / (float)B_);
}

extern "C" void kernel_launch(void* const* d_in, const int* in_sizes, int n_in,
                              void* d_out, int out_size, void* d_ws, size_t ws_size,
                              hipStream_t stream) {
    const int* sentence = (const int*)d_in[0];
    const int* tags = (const int*)d_in[1];
    const void* mask = d_in[2];
    const float* embedding = (const float*)d_in[3];
    const float* W_ih = (const float*)d_in[4];
    const float* W_hh = (const float*)d_in[5];
    const float* b_ih = (const float*)d_in[6];
    const float* b_hh = (const float*)d_in[7];
    const float* W_dec = (const float*)d_in[8];
    const float* b_dec = (const float*)d_in[9];
    const float* start_trans = (const float*)d_in[10];
    const float* end_trans = (const float*)d_in[11];
    const float* trans = (const float*)d_in[12];

    char* ws = (char*)d_ws;
    int* flag = (int*)ws;                                   // 4 B (pad to 256)
    __hip_bfloat16* xg = (__hip_bfloat16*)(ws + 256);       // B*S*512 bf16 = 64 MiB
    size_t off = 256 + (size_t)B_ * S_ * G4_ * 2;
    float* em = (float*)(ws + off);                         // B*S*20 f32 = 5 MiB
    off += (size_t)B_ * S_ * NT_ * 4;
    float* nllp = (float*)(ws + off);                       // 128 f32 (pad 512)
    off += 512;
    unsigned* h2_out = (unsigned*)(ws + off);               // B*S*64 u32 = 16 MiB
    off += (size_t)B_ * S_ * 64 * 4;
    __hip_bfloat16* Wb = (__hip_bfloat16*)(ws + off);       // 512*224 bf16 = 224 KB
    off += (size_t)G4_ * KP_ * 2;
    float* biasb = (float*)(ws + off);                      // 512 f32

    k_detect<<<1, 256, 0, stream>>>((const unsigned char*)mask, flag);
    k_prep<<<(G4_ * KP_ + 255) / 256, 256, 0, stream>>>(W_ih, b_ih, b_hh, Wb, biasb);
    k_xg<<<(B_ * S_) / 32, 256, 0, stream>>>(sentence, embedding, Wb, biasb, xg);
    k_lstm<<<B_, 1024, 0, stream>>>(xg, W_hh, h2_out);
    k_em<<<(B_ * S_) / 16, 320, 0, stream>>>(h2_out, W_dec, b_dec, em);
    k_crf<<<B_, 64, 0, stream>>>(em, tags, mask, flag, start_trans, end_trans, trans, nllp);
    k_final<<<1, 128, 0, stream>>>(nllp, (float*)d_out);
}